// Round 3
// baseline (829.019 us; speedup 1.0000x reference)
//
#include <hip/hip_runtime.h>

#define EXT 40
#define SQ (EXT*EXT)

__device__ __forceinline__ unsigned um_min(unsigned a, unsigned b){ return a < b ? a : b; }
__device__ __forceinline__ unsigned um_max(unsigned a, unsigned b){ return a > b ? a : b; }
__device__ __forceinline__ unsigned med3u(unsigned a, unsigned b, unsigned c){
  unsigned d;
  asm("v_med3_u32 %0, %1, %2, %3" : "=v"(d) : "v"(a), "v"(b), "v"(c));
  return d;
}

// arr sorted descending (arr[0] = largest of the kept 14 smallest).
// Insert key, drop the max of the 15. med3 network: 15 ops, dep depth 2.
__device__ __forceinline__ void insert14(unsigned (&a)[14], unsigned key){
  unsigned kp  = um_min(key, a[0]);
  unsigned n0  = um_max(a[1], kp);
  unsigned n13 = um_min(a[13], kp);
  unsigned nn[12];
  #pragma unroll
  for (int i = 1; i <= 12; ++i) nn[i-1] = med3u(a[i], a[i+1], kp);
  a[0] = n0;
  #pragma unroll
  for (int i = 1; i <= 12; ++i) a[i] = nn[i-1];
  a[13] = n13;
}

// Reflect-padded rescaled image Xp[3][288][288] (means cancel -> skipped),
// plus zero-init of the global fold accumulator.
__global__ void k_prep(const float* __restrict__ noisy, float* __restrict__ Xp,
                       float* __restrict__ accG){
  int idx = blockIdx.x * 256 + threadIdx.x;
  if (idx < 3*260*260) accG[idx] = 0.f;
  if (idx >= 288*288) return;
  int P = idx / 288, Q = idx - P*288;
  int sy = P - 16; sy = sy < 0 ? -sy : sy; sy = sy > 255 ? 510 - sy : sy;
  int sx = Q - 16; sx = sx < 0 ? -sx : sx; sx = sx > 255 ? 510 - sx : sx;
  const float inv = 1.0f / 127.5f;
  int src = sy*256 + sx;
  #pragma unroll
  for (int c = 0; c < 3; ++c)
    Xp[c*82944 + idx] = noisy[c*65536 + src] * inv - 1.0f;
}

// One dx step, fully unrolled (DX compile-time -> ds_read offsets are immediates).
// SSD by expansion: dist = cpsq + winsq - 2*cross, winsq kept as rolling column-ssq sum.
template<int DX>
__device__ __forceinline__ void ssd_step(const float* rowbase, unsigned obase,
                                         const float (&cp)[5][5], float cpsq,
                                         float (&win)[5][5], float (&ring)[5],
                                         float& winsq, unsigned (&arr)[14]){
  constexpr int nc = (DX + 4) % 5;
  #pragma unroll
  for (int u = 0; u < 5; ++u) win[u][nc] = rowbase[u*EXT + DX + 4];
  float nssq = win[0][nc]*win[0][nc];
  #pragma unroll
  for (int u = 1; u < 5; ++u) nssq = fmaf(win[u][nc], win[u][nc], nssq);
  winsq += (nssq - ring[nc]);
  ring[nc] = nssq;
  float c0=0.f, c1=0.f, c2=0.f, c3=0.f, c4=0.f;
  #pragma unroll
  for (int v = 0; v < 5; ++v){
    c0 = fmaf(cp[0][v], win[0][(DX + v) % 5], c0);
    c1 = fmaf(cp[1][v], win[1][(DX + v) % 5], c1);
    c2 = fmaf(cp[2][v], win[2][(DX + v) % 5], c2);
    c3 = fmaf(cp[3][v], win[3][(DX + v) % 5], c3);
    c4 = fmaf(cp[4][v], win[4][(DX + v) % 5], c4);
  }
  float cross = ((c0 + c1) + (c2 + c3)) + c4;
  float dist = fmaf(cross, -2.0f, cpsq + winsq);
  dist = fmaxf(dist, 0.0f);   // cancellation guard
  insert14(arr, (__float_as_uint(dist) & 0xFFFFFC00u) | (obase + (unsigned)DX));
}

template<int DX>
__device__ __forceinline__ void row_steps(const float* rowbase, unsigned obase,
                                          const float (&cp)[5][5], float cpsq,
                                          float (&win)[5][5], float (&ring)[5],
                                          float& winsq, unsigned (&arr)[14]){
  if constexpr (DX < 29){
    ssd_step<DX>(rowbase, obase, cp, cpsq, win, ring, winsq, arr);
    row_steps<DX+1>(rowbase, obase, cp, cpsq, win, ring, winsq, arr);
  }
}

// One 8x8 pixel tile per 512-thread block; 8 waves split the 29 dy rows.
// LDS overlay: uni[] holds per-wave candidates at merge time, then the color
// tile during phase-2 aggregation (sCand is fully consumed before restaging).
__global__ __launch_bounds__(512, 8) void k_search(const float* __restrict__ Xp,
      const float* __restrict__ sigma, const float* __restrict__ wgray,
      float* __restrict__ accG){
  __shared__ float sG[SQ];           //  6400 B grayscale tile
  __shared__ float uni[3*SQ];        // 19200 B union: sCand (14336 B) / sXp
  __shared__ float sWsum[64];
  __shared__ float sFold[12*12*3];

  unsigned* sCand = (unsigned*)uni;
  float*    sXp   = uni;

  const int tid = threadIdx.x;
  const int w = tid >> 6, l = tid & 63;
  const int ly = l >> 3, lx = l & 7;
  const int bi = blockIdx.y * 8, bj = blockIdx.x * 8;

  if (tid < 64) sWsum[tid] = 0.f;
  if (tid < 432) sFold[tid] = 0.f;
  // grayscale tile straight from global (L2-hot)
  const float w0 = wgray[0], w1 = wgray[1], w2 = wgray[2];
  for (int t = tid; t < SQ; t += 512){
    int rr = t / EXT, cc = t - rr*EXT;
    int base = (bi+rr)*288 + (bj+cc);
    sG[t] = w0*Xp[base] + w1*Xp[82944 + base] + w2*Xp[2*82944 + base];
  }
  __syncthreads();

  // center 5x5 grayscale patch + squared norm
  float cp[5][5];
  #pragma unroll
  for (int u = 0; u < 5; ++u)
    #pragma unroll
    for (int v = 0; v < 5; ++v)
      cp[u][v] = sG[(14 + ly + u)*EXT + 14 + lx + v];
  float cpsq = 0.f;
  #pragma unroll
  for (int v = 0; v < 5; ++v){
    float cs = cp[0][v]*cp[0][v];
    #pragma unroll
    for (int u = 1; u < 5; ++u) cs = fmaf(cp[u][v], cp[u][v], cs);
    cpsq += cs;
  }

  unsigned arr[14];
  #pragma unroll
  for (int k = 0; k < 14; ++k) arr[k] = 0xFFFFFFFFu;

  // rows per wave: {4,4,4,4,4,3,3,3}
  const int dy0 = (w < 5) ? w*4 : 20 + (w-5)*3;
  const int nrows = (w < 5) ? 4 : 3;

  #pragma unroll 1
  for (int r = 0; r < nrows; ++r){
    const int dy = dy0 + r;
    const float* rowbase = &sG[(dy + ly)*EXT + lx];
    float win[5][5], ring[5], winsq;
    #pragma unroll
    for (int v = 0; v < 4; ++v){
      #pragma unroll
      for (int u = 0; u < 5; ++u) win[u][v] = rowbase[u*EXT + v];
      float cs = win[0][v]*win[0][v];
      #pragma unroll
      for (int u = 1; u < 5; ++u) cs = fmaf(win[u][v], win[u][v], cs);
      ring[v] = cs;
    }
    ring[4] = 0.f;
    winsq = (ring[0] + ring[1]) + (ring[2] + ring[3]);
    row_steps<0>(rowbase, (unsigned)(dy*29), cp, cpsq, win, ring, winsq, arr);
  }

  // ---- tree merge 8 -> 4 -> 2 -> 1 (regions of 896 u32 in sCand) ----
  if (w >= 4){
    #pragma unroll
    for (int k = 0; k < 14; ++k) sCand[(w-4)*896 + l*14 + k] = arr[k];
  }
  __syncthreads();
  if (w < 4){
    #pragma unroll
    for (int k = 0; k < 14; ++k) insert14(arr, sCand[w*896 + l*14 + k]);
  }
  __syncthreads();
  if (w == 2 || w == 3){
    #pragma unroll
    for (int k = 0; k < 14; ++k) sCand[(w-2)*896 + l*14 + k] = arr[k];
  }
  __syncthreads();
  if (w < 2){
    #pragma unroll
    for (int k = 0; k < 14; ++k) insert14(arr, sCand[w*896 + l*14 + k]);
  }
  __syncthreads();
  if (w == 1){
    #pragma unroll
    for (int k = 0; k < 14; ++k) sCand[l*14 + k] = arr[k];
  }
  __syncthreads();
  if (w == 0){
    #pragma unroll
    for (int k = 0; k < 14; ++k) insert14(arr, sCand[l*14 + k]);
    #pragma unroll
    for (int k = 0; k < 14; ++k) sCand[l*14 + k] = arr[k];
  }
  __syncthreads();

  // ---- phase 2: weights (read sCand), then restage color tile over it ----
  float sg = sigma[0] * (1.0f / 127.5f);
  const float invT = 1.0f / (sg*sg*25.0f + 1e-8f);
  const float dmin = __uint_as_float(sCand[l*14 + 13] & 0xFFFFFC00u);

  // neighbor ranks per wave: {w, w+8} for w<6, {w} for w>=6  (covers 0..13)
  const int nk = (w < 6) ? 2 : 1;
  float wgt[2]; int ndy[2], ndx[2];
  float Sp = 0.f;
  #pragma unroll
  for (int m = 0; m < 2; ++m){
    if (m < nk){
      unsigned kk = sCand[l*14 + (m ? w + 8 : w)];
      float d = __uint_as_float(kk & 0xFFFFFC00u);
      int o = (int)(kk & 0x3FFu);
      wgt[m] = expf(-(d - dmin) * invT);
      ndy[m] = o / 29; ndx[m] = o - ndy[m]*29;
      Sp += wgt[m];
    }
  }
  atomicAdd(&sWsum[l], Sp);
  __syncthreads();                       // sCand consumed + sWsum complete
  const float invS = 1.0f / sWsum[l];
  #pragma unroll
  for (int m = 0; m < 2; ++m) if (m < nk) wgt[m] *= invS;

  // stage color tile into the union region (coalesced)
  for (int t = tid; t < 3*SQ; t += 512){
    int c = t / SQ; int r2 = t - c*SQ; int rr = r2 / EXT; int cc = r2 - rr*EXT;
    sXp[t] = Xp[c*82944 + (bi+rr)*288 + (bj+cc)];
  }
  __syncthreads();

  #pragma unroll
  for (int c = 0; c < 3; ++c){
    float acc[5][5];
    #pragma unroll
    for (int u = 0; u < 5; ++u)
      #pragma unroll
      for (int v = 0; v < 5; ++v) acc[u][v] = 0.f;
    #pragma unroll
    for (int m = 0; m < 2; ++m){
      if (m < nk){
        const float* pb = &sXp[c*SQ + (ly + ndy[m])*EXT + lx + ndx[m]];
        float g = wgt[m];
        #pragma unroll
        for (int u = 0; u < 5; ++u)
          #pragma unroll
          for (int v = 0; v < 5; ++v)
            acc[u][v] = fmaf(g, pb[u*EXT + v], acc[u][v]);
      }
    }
    #pragma unroll
    for (int u = 0; u < 5; ++u)
      #pragma unroll
      for (int v = 0; v < 5; ++v)
        atomicAdd(&sFold[((ly+u)*12 + (lx+v))*3 + c], acc[u][v]);
  }
  __syncthreads();
  for (int t = tid; t < 432; t += 512){
    int c = t % 3; int rc = t / 3; int rr = rc / 12; int cc = rc - rr*12;
    atomicAdd(&accG[c*67600 + (bi+rr)*260 + (bj+cc)], sFold[t]);
  }
}

__global__ void k_finish(const float* __restrict__ accG, float* __restrict__ out){
  int idx = blockIdx.x * 256 + threadIdx.x;
  if (idx >= 3*65536) return;
  int c = idx >> 16; int rem = idx & 65535; int y = rem >> 8; int x = rem & 255;
  int cy = min(4, y + 2) - max(0, y - 253) + 1;
  int cx = min(4, x + 2) - max(0, x - 253) + 1;
  float v = accG[c*67600 + (y+2)*260 + (x+2)] / (float)(cy * cx);
  out[idx] = 127.5f * v + 127.5f;
}

extern "C" void kernel_launch(void* const* d_in, const int* in_sizes, int n_in,
                              void* d_out, int out_size, void* d_ws, size_t ws_size,
                              hipStream_t stream) {
  const float* noisy = (const float*)d_in[0];
  const float* sigma = (const float*)d_in[1];
  const float* wgray = (const float*)d_in[2];
  float* out  = (float*)d_out;
  float* Xp   = (float*)d_ws;                  // 3*288*288 floats
  float* accG = Xp + 3*288*288;                // 3*260*260 floats

  k_prep<<<dim3(793), dim3(256), 0, stream>>>(noisy, Xp, accG);
  k_search<<<dim3(32, 32), dim3(512), 0, stream>>>(Xp, sigma, wgray, accG);
  k_finish<<<dim3(768), dim3(256), 0, stream>>>(accG, out);
}

// Round 4
// 396.267 us; speedup vs baseline: 2.0921x; 2.0921x over previous
//
#include <hip/hip_runtime.h>

#define EXT 40
#define SQ (EXT*EXT)

__device__ __forceinline__ unsigned um_min(unsigned a, unsigned b){ return a < b ? a : b; }
__device__ __forceinline__ unsigned um_max(unsigned a, unsigned b){ return a > b ? a : b; }
__device__ __forceinline__ unsigned med3u(unsigned a, unsigned b, unsigned c){
  unsigned d;
  asm("v_med3_u32 %0, %1, %2, %3" : "=v"(d) : "v"(a), "v"(b), "v"(c));
  return d;
}

// arr sorted descending (arr[0] = largest of the kept 14 smallest).
// Insert key, drop the max of the 15. med3 network: 15 ops, dep depth 2.
__device__ __forceinline__ void insert14(unsigned (&a)[14], unsigned key){
  unsigned kp  = um_min(key, a[0]);
  unsigned n0  = um_max(a[1], kp);
  unsigned n13 = um_min(a[13], kp);
  unsigned nn[12];
  #pragma unroll
  for (int i = 1; i <= 12; ++i) nn[i-1] = med3u(a[i], a[i+1], kp);
  a[0] = n0;
  #pragma unroll
  for (int i = 1; i <= 12; ++i) a[i] = nn[i-1];
  a[13] = n13;
}

// Reflect-padded rescaled image Xp[3][288][288] (means cancel -> skipped),
// plus zero-init of the global fold accumulator.
__global__ void k_prep(const float* __restrict__ noisy, float* __restrict__ Xp,
                       float* __restrict__ accG){
  int idx = blockIdx.x * 256 + threadIdx.x;
  if (idx < 3*260*260) accG[idx] = 0.f;
  if (idx >= 288*288) return;
  int P = idx / 288, Q = idx - P*288;
  int sy = P - 16; sy = sy < 0 ? -sy : sy; sy = sy > 255 ? 510 - sy : sy;
  int sx = Q - 16; sx = sx < 0 ? -sx : sx; sx = sx > 255 ? 510 - sx : sx;
  const float inv = 1.0f / 127.5f;
  int src = sy*256 + sx;
  #pragma unroll
  for (int c = 0; c < 3; ++c)
    Xp[c*82944 + idx] = noisy[c*65536 + src] * inv - 1.0f;
}

// One dx step, fully unrolled (DX compile-time -> ds_read offsets are immediates).
// SSD by expansion: dist = cpsq + winsq - 2*cross, winsq kept as rolling column-ssq sum.
template<int DX>
__device__ __forceinline__ void ssd_step(const float* rowbase, unsigned obase,
                                         const float (&cp)[5][5], float cpsq,
                                         float (&win)[5][5], float (&ring)[5],
                                         float& winsq, unsigned (&arr)[14]){
  constexpr int nc = (DX + 4) % 5;
  #pragma unroll
  for (int u = 0; u < 5; ++u) win[u][nc] = rowbase[u*EXT + DX + 4];
  float nssq = win[0][nc]*win[0][nc];
  #pragma unroll
  for (int u = 1; u < 5; ++u) nssq = fmaf(win[u][nc], win[u][nc], nssq);
  winsq += (nssq - ring[nc]);
  ring[nc] = nssq;
  float c0=0.f, c1=0.f, c2=0.f, c3=0.f, c4=0.f;
  #pragma unroll
  for (int v = 0; v < 5; ++v){
    c0 = fmaf(cp[0][v], win[0][(DX + v) % 5], c0);
    c1 = fmaf(cp[1][v], win[1][(DX + v) % 5], c1);
    c2 = fmaf(cp[2][v], win[2][(DX + v) % 5], c2);
    c3 = fmaf(cp[3][v], win[3][(DX + v) % 5], c3);
    c4 = fmaf(cp[4][v], win[4][(DX + v) % 5], c4);
  }
  float cross = ((c0 + c1) + (c2 + c3)) + c4;
  float dist = fmaf(cross, -2.0f, cpsq + winsq);
  dist = fmaxf(dist, 0.0f);   // cancellation guard
  insert14(arr, (__float_as_uint(dist) & 0xFFFFFC00u) | (obase + (unsigned)DX));
}

template<int DX>
__device__ __forceinline__ void row_steps(const float* rowbase, unsigned obase,
                                          const float (&cp)[5][5], float cpsq,
                                          float (&win)[5][5], float (&ring)[5],
                                          float& winsq, unsigned (&arr)[14]){
  if constexpr (DX < 29){
    ssd_step<DX>(rowbase, obase, cp, cpsq, win, ring, winsq, arr);
    row_steps<DX+1>(rowbase, obase, cp, cpsq, win, ring, winsq, arr);
  }
}

// One 8x8 pixel tile per 256-thread block; 4 waves split the 29 dy rows.
// LDS overlays: uni[] = sCand (merge) then color tile (phase 2);
//               sG[] = grayscale tile (search) then sWsum+sFold (phase 2).
// 25.6 KB LDS -> 6 blocks/CU (24 waves, 75%); VGPR cap 84 via (256,6) -> no spills.
__global__ __launch_bounds__(256, 6) void k_search(const float* __restrict__ Xp,
      const float* __restrict__ sigma, const float* __restrict__ wgray,
      float* __restrict__ accG){
  __shared__ float sG[SQ];           //  6400 B gray tile | phase2: sWsum(64)+sFold(432)
  __shared__ float uni[3*SQ];        // 19200 B sCand (10752 B) | phase2: color tile

  unsigned* sCand = (unsigned*)uni;
  float*    sXp   = uni;
  float*    sWsum = sG;
  float*    sFold = sG + 64;

  const int tid = threadIdx.x;
  const int w = tid >> 6, l = tid & 63;
  const int ly = l >> 3, lx = l & 7;
  const int bi = blockIdx.y * 8, bj = blockIdx.x * 8;

  // grayscale tile straight from global (L2-hot)
  const float w0 = wgray[0], w1 = wgray[1], w2 = wgray[2];
  for (int t = tid; t < SQ; t += 256){
    int rr = t / EXT, cc = t - rr*EXT;
    int base = (bi+rr)*288 + (bj+cc);
    sG[t] = w0*Xp[base] + w1*Xp[82944 + base] + w2*Xp[165888 + base];
  }
  __syncthreads();

  // center 5x5 grayscale patch + squared norm
  float cp[5][5];
  #pragma unroll
  for (int u = 0; u < 5; ++u)
    #pragma unroll
    for (int v = 0; v < 5; ++v)
      cp[u][v] = sG[(14 + ly + u)*EXT + 14 + lx + v];
  float cpsq = 0.f;
  #pragma unroll
  for (int v = 0; v < 5; ++v){
    float cs = cp[0][v]*cp[0][v];
    #pragma unroll
    for (int u = 1; u < 5; ++u) cs = fmaf(cp[u][v], cp[u][v], cs);
    cpsq += cs;
  }

  unsigned arr[14];
  #pragma unroll
  for (int k = 0; k < 14; ++k) arr[k] = 0xFFFFFFFFu;

  // rows per wave: {8,7,7,7}
  const int dy0 = (w == 0) ? 0 : 1 + 7*w;
  const int dy1 = dy0 + ((w == 0) ? 8 : 7);

  #pragma unroll 1
  for (int dy = dy0; dy < dy1; ++dy){
    const float* rowbase = &sG[(dy + ly)*EXT + lx];
    float win[5][5], ring[5], winsq;
    #pragma unroll
    for (int v = 0; v < 4; ++v){
      #pragma unroll
      for (int u = 0; u < 5; ++u) win[u][v] = rowbase[u*EXT + v];
      float cs = win[0][v]*win[0][v];
      #pragma unroll
      for (int u = 1; u < 5; ++u) cs = fmaf(win[u][v], win[u][v], cs);
      ring[v] = cs;
    }
    ring[4] = 0.f;
    winsq = (ring[0] + ring[1]) + (ring[2] + ring[3]);
    row_steps<0>(rowbase, (unsigned)(dy*29), cp, cpsq, win, ring, winsq, arr);
  }

  // merge: waves 1-3 store; all search reads of sG complete at this barrier
  if (w){
    #pragma unroll
    for (int k = 0; k < 14; ++k) sCand[((w-1)*64 + l)*14 + k] = arr[k];
  }
  __syncthreads();
  // sG dead -> init phase-2 accumulators in its space (all waves)
  for (int t = tid; t < 496; t += 256) sG[t] = 0.f;
  if (!w){
    for (int q = 0; q < 3; ++q)
      #pragma unroll
      for (int k = 0; k < 14; ++k)
        insert14(arr, sCand[(q*64 + l)*14 + k]);
    #pragma unroll
    for (int k = 0; k < 14; ++k) sCand[l*14 + k] = arr[k];
  }
  __syncthreads();

  // ---- phase 2: softmax weights (last sCand reads) ----
  float sg = sigma[0] * (1.0f / 127.5f);
  const float invT = 1.0f / (sg*sg*25.0f + 1e-8f);
  const float dmin = __uint_as_float(sCand[l*14 + 13] & 0xFFFFFC00u);

  float wgt[4]; int ndy[4], ndx[4];
  const int nk = (w < 2) ? 4 : 3;          // ranks {w, w+4, w+8, (w+12)}
  float Sp = 0.f;
  #pragma unroll
  for (int m = 0; m < 4; ++m){
    if (m < nk){
      unsigned kk = sCand[l*14 + (w + 4*m)];
      float d = __uint_as_float(kk & 0xFFFFFC00u);
      int o = (int)(kk & 0x3FFu);
      wgt[m] = expf(-(d - dmin) * invT);
      ndy[m] = o / 29; ndx[m] = o - ndy[m]*29;
      Sp += wgt[m];
    }
  }
  atomicAdd(&sWsum[l], Sp);
  __syncthreads();                       // sCand fully consumed; sWsum complete
  const float invS = 1.0f / sWsum[l];
  #pragma unroll
  for (int m = 0; m < 4; ++m) if (m < nk) wgt[m] *= invS;

  // stage color tile over the candidate region (coalesced, L2-hot)
  for (int t = tid; t < 3*SQ; t += 256){
    int c = t / SQ; int r2 = t - c*SQ; int rr = r2 / EXT; int cc = r2 - rr*EXT;
    sXp[t] = Xp[c*82944 + (bi+rr)*288 + (bj+cc)];
  }
  __syncthreads();

  #pragma unroll
  for (int c = 0; c < 3; ++c){
    float acc[5][5];
    #pragma unroll
    for (int u = 0; u < 5; ++u)
      #pragma unroll
      for (int v = 0; v < 5; ++v) acc[u][v] = 0.f;
    #pragma unroll
    for (int m = 0; m < 4; ++m){
      if (m < nk){
        const float* pb = &sXp[c*SQ + (ly + ndy[m])*EXT + lx + ndx[m]];
        float g = wgt[m];
        #pragma unroll
        for (int u = 0; u < 5; ++u)
          #pragma unroll
          for (int v = 0; v < 5; ++v)
            acc[u][v] = fmaf(g, pb[u*EXT + v], acc[u][v]);
      }
    }
    #pragma unroll
    for (int u = 0; u < 5; ++u)
      #pragma unroll
      for (int v = 0; v < 5; ++v)
        atomicAdd(&sFold[((ly+u)*12 + (lx+v))*3 + c], acc[u][v]);
  }
  __syncthreads();
  for (int t = tid; t < 432; t += 256){
    int c = t % 3; int rc = t / 3; int rr = rc / 12; int cc = rc - rr*12;
    atomicAdd(&accG[c*67600 + (bi+rr)*260 + (bj+cc)], sFold[t]);
  }
}

__global__ void k_finish(const float* __restrict__ accG, float* __restrict__ out){
  int idx = blockIdx.x * 256 + threadIdx.x;
  if (idx >= 3*65536) return;
  int c = idx >> 16; int rem = idx & 65535; int y = rem >> 8; int x = rem & 255;
  int cy = min(4, y + 2) - max(0, y - 253) + 1;
  int cx = min(4, x + 2) - max(0, x - 253) + 1;
  float v = accG[c*67600 + (y+2)*260 + (x+2)] / (float)(cy * cx);
  out[idx] = 127.5f * v + 127.5f;
}

extern "C" void kernel_launch(void* const* d_in, const int* in_sizes, int n_in,
                              void* d_out, int out_size, void* d_ws, size_t ws_size,
                              hipStream_t stream) {
  const float* noisy = (const float*)d_in[0];
  const float* sigma = (const float*)d_in[1];
  const float* wgray = (const float*)d_in[2];
  float* out  = (float*)d_out;
  float* Xp   = (float*)d_ws;                  // 3*288*288 floats
  float* accG = Xp + 3*288*288;                // 3*260*260 floats

  k_prep<<<dim3(793), dim3(256), 0, stream>>>(noisy, Xp, accG);
  k_search<<<dim3(32, 32), dim3(256), 0, stream>>>(Xp, sigma, wgray, accG);
  k_finish<<<dim3(768), dim3(256), 0, stream>>>(accG, out);
}

// Round 5
// 334.654 us; speedup vs baseline: 2.4772x; 1.1841x over previous
//
#include <hip/hip_runtime.h>

#define EXT 40
#define SQ (EXT*EXT)

__device__ __forceinline__ unsigned um_min(unsigned a, unsigned b){ return a < b ? a : b; }
__device__ __forceinline__ unsigned um_max(unsigned a, unsigned b){ return a > b ? a : b; }
__device__ __forceinline__ unsigned med3u(unsigned a, unsigned b, unsigned c){
  unsigned d;
  asm("v_med3_u32 %0, %1, %2, %3" : "=v"(d) : "v"(a), "v"(b), "v"(c));
  return d;
}

// arr sorted descending (arr[0] = largest of the kept 14 smallest).
// Insert key, drop the max of the 15. med3 network: 15 ops, dep depth 2.
__device__ __forceinline__ void insert14(unsigned (&a)[14], unsigned key){
  unsigned kp  = um_min(key, a[0]);
  unsigned n0  = um_max(a[1], kp);
  unsigned n13 = um_min(a[13], kp);
  unsigned nn[12];
  #pragma unroll
  for (int i = 1; i <= 12; ++i) nn[i-1] = med3u(a[i], a[i+1], kp);
  a[0] = n0;
  #pragma unroll
  for (int i = 1; i <= 12; ++i) a[i] = nn[i-1];
  a[13] = n13;
}

// Reflect-padded rescaled image Xp[3][288][288] (means cancel -> skipped),
// plus zero-init of the global fold accumulator.
__global__ void k_prep(const float* __restrict__ noisy, float* __restrict__ Xp,
                       float* __restrict__ accG){
  int idx = blockIdx.x * 256 + threadIdx.x;
  if (idx < 3*260*260) accG[idx] = 0.f;
  if (idx >= 288*288) return;
  int P = idx / 288, Q = idx - P*288;
  int sy = P - 16; sy = sy < 0 ? -sy : sy; sy = sy > 255 ? 510 - sy : sy;
  int sx = Q - 16; sx = sx < 0 ? -sx : sx; sx = sx > 255 ? 510 - sx : sx;
  const float inv = 1.0f / 127.5f;
  int src = sy*256 + sx;
  #pragma unroll
  for (int c = 0; c < 3; ++c)
    Xp[c*82944 + idx] = noisy[c*65536 + src] * inv - 1.0f;
}

// One dx step, fully unrolled (DX compile-time -> ds_read offsets are immediates).
// SSD by expansion: dist = cpsq + winsq - 2*cross, winsq kept as rolling column-ssq sum.
template<int DX>
__device__ __forceinline__ void ssd_step(const float* rowbase, unsigned obase,
                                         const float (&cp)[5][5], float cpsq,
                                         float (&win)[5][5], float (&ring)[5],
                                         float& winsq, unsigned (&arr)[14]){
  constexpr int nc = (DX + 4) % 5;
  #pragma unroll
  for (int u = 0; u < 5; ++u) win[u][nc] = rowbase[u*EXT + DX + 4];
  float nssq = win[0][nc]*win[0][nc];
  #pragma unroll
  for (int u = 1; u < 5; ++u) nssq = fmaf(win[u][nc], win[u][nc], nssq);
  winsq += (nssq - ring[nc]);
  ring[nc] = nssq;
  float c0=0.f, c1=0.f, c2=0.f, c3=0.f, c4=0.f;
  #pragma unroll
  for (int v = 0; v < 5; ++v){
    c0 = fmaf(cp[0][v], win[0][(DX + v) % 5], c0);
    c1 = fmaf(cp[1][v], win[1][(DX + v) % 5], c1);
    c2 = fmaf(cp[2][v], win[2][(DX + v) % 5], c2);
    c3 = fmaf(cp[3][v], win[3][(DX + v) % 5], c3);
    c4 = fmaf(cp[4][v], win[4][(DX + v) % 5], c4);
  }
  float cross = ((c0 + c1) + (c2 + c3)) + c4;
  float dist = fmaf(cross, -2.0f, cpsq + winsq);
  dist = fmaxf(dist, 0.0f);   // cancellation guard
  insert14(arr, (__float_as_uint(dist) & 0xFFFFFC00u) | (obase + (unsigned)DX));
}

template<int DX>
__device__ __forceinline__ void row_steps(const float* rowbase, unsigned obase,
                                          const float (&cp)[5][5], float cpsq,
                                          float (&win)[5][5], float (&ring)[5],
                                          float& winsq, unsigned (&arr)[14]){
  if constexpr (DX < 29){
    ssd_step<DX>(rowbase, obase, cp, cpsq, win, ring, winsq, arr);
    row_steps<DX+1>(rowbase, obase, cp, cpsq, win, ring, winsq, arr);
  }
}

// One 8x8 pixel tile per 512-thread block; 8 waves split the 29 dy rows.
// launch_bounds(512,4): VGPR cap 128 -> allocator lands at natural ~64 (R2-proven),
// giving 8 waves/SIMD slots; 4 blocks/CU resident (whole 1024-block grid at once).
// LDS overlay: uni[] = per-wave candidates during merge, color tile in phase 2.
__global__ __launch_bounds__(512, 4) void k_search(const float* __restrict__ Xp,
      const float* __restrict__ sigma, const float* __restrict__ wgray,
      float* __restrict__ accG){
  __shared__ float sG[SQ];           //  6400 B grayscale tile
  __shared__ float uni[3*SQ];        // 19200 B union: sCand (14336 B) / sXp
  __shared__ float sWsum[64];
  __shared__ float sFold[12*12*3];

  unsigned* sCand = (unsigned*)uni;
  float*    sXp   = uni;

  const int tid = threadIdx.x;
  const int w = tid >> 6, l = tid & 63;
  const int ly = l >> 3, lx = l & 7;
  const int bi = blockIdx.y * 8, bj = blockIdx.x * 8;

  if (tid < 64) sWsum[tid] = 0.f;
  if (tid < 432) sFold[tid] = 0.f;
  // grayscale tile straight from global (L2-hot)
  const float w0 = wgray[0], w1 = wgray[1], w2 = wgray[2];
  for (int t = tid; t < SQ; t += 512){
    int rr = t / EXT, cc = t - rr*EXT;
    int base = (bi+rr)*288 + (bj+cc);
    sG[t] = w0*Xp[base] + w1*Xp[82944 + base] + w2*Xp[165888 + base];
  }
  __syncthreads();

  // center 5x5 grayscale patch + squared norm
  float cp[5][5];
  #pragma unroll
  for (int u = 0; u < 5; ++u)
    #pragma unroll
    for (int v = 0; v < 5; ++v)
      cp[u][v] = sG[(14 + ly + u)*EXT + 14 + lx + v];
  float cpsq = 0.f;
  #pragma unroll
  for (int v = 0; v < 5; ++v){
    float cs = cp[0][v]*cp[0][v];
    #pragma unroll
    for (int u = 1; u < 5; ++u) cs = fmaf(cp[u][v], cp[u][v], cs);
    cpsq += cs;
  }

  unsigned arr[14];
  #pragma unroll
  for (int k = 0; k < 14; ++k) arr[k] = 0xFFFFFFFFu;

  // rows per wave: {4,4,4,4,4,3,3,3}
  const int dy0 = (w < 5) ? w*4 : 20 + (w-5)*3;
  const int nrows = (w < 5) ? 4 : 3;

  #pragma unroll 1
  for (int r = 0; r < nrows; ++r){
    const int dy = dy0 + r;
    const float* rowbase = &sG[(dy + ly)*EXT + lx];
    float win[5][5], ring[5], winsq;
    #pragma unroll
    for (int v = 0; v < 4; ++v){
      #pragma unroll
      for (int u = 0; u < 5; ++u) win[u][v] = rowbase[u*EXT + v];
      float cs = win[0][v]*win[0][v];
      #pragma unroll
      for (int u = 1; u < 5; ++u) cs = fmaf(win[u][v], win[u][v], cs);
      ring[v] = cs;
    }
    ring[4] = 0.f;
    winsq = (ring[0] + ring[1]) + (ring[2] + ring[3]);
    row_steps<0>(rowbase, (unsigned)(dy*29), cp, cpsq, win, ring, winsq, arr);
  }

  // ---- tree merge 8 -> 4 -> 2 -> 1 (regions of 896 u32 in sCand) ----
  if (w >= 4){
    #pragma unroll
    for (int k = 0; k < 14; ++k) sCand[(w-4)*896 + l*14 + k] = arr[k];
  }
  __syncthreads();
  if (w < 4){
    #pragma unroll
    for (int k = 0; k < 14; ++k) insert14(arr, sCand[w*896 + l*14 + k]);
  }
  __syncthreads();
  if (w == 2 || w == 3){
    #pragma unroll
    for (int k = 0; k < 14; ++k) sCand[(w-2)*896 + l*14 + k] = arr[k];
  }
  __syncthreads();
  if (w < 2){
    #pragma unroll
    for (int k = 0; k < 14; ++k) insert14(arr, sCand[w*896 + l*14 + k]);
  }
  __syncthreads();
  if (w == 1){
    #pragma unroll
    for (int k = 0; k < 14; ++k) sCand[l*14 + k] = arr[k];
  }
  __syncthreads();
  if (w == 0){
    #pragma unroll
    for (int k = 0; k < 14; ++k) insert14(arr, sCand[l*14 + k]);
    #pragma unroll
    for (int k = 0; k < 14; ++k) sCand[l*14 + k] = arr[k];
  }
  __syncthreads();

  // ---- phase 2: softmax weights (last sCand reads) ----
  float sg = sigma[0] * (1.0f / 127.5f);
  const float invT = 1.0f / (sg*sg*25.0f + 1e-8f);
  const float dmin = __uint_as_float(sCand[l*14 + 13] & 0xFFFFFC00u);

  // neighbor ranks per wave: {w, w+8} for w<6, {w} for w>=6 (covers 0..13)
  const int nk = (w < 6) ? 2 : 1;
  float wgt[2]; int ndy[2], ndx[2];
  float Sp = 0.f;
  #pragma unroll
  for (int m = 0; m < 2; ++m){
    if (m < nk){
      unsigned kk = sCand[l*14 + (m ? w + 8 : w)];
      float d = __uint_as_float(kk & 0xFFFFFC00u);
      int o = (int)(kk & 0x3FFu);
      wgt[m] = expf(-(d - dmin) * invT);
      ndy[m] = o / 29; ndx[m] = o - ndy[m]*29;
      Sp += wgt[m];
    }
  }
  atomicAdd(&sWsum[l], Sp);
  __syncthreads();                       // sCand fully consumed; sWsum complete
  const float invS = 1.0f / sWsum[l];
  #pragma unroll
  for (int m = 0; m < 2; ++m) if (m < nk) wgt[m] *= invS;

  // stage color tile into the union region (coalesced, L2-hot)
  for (int t = tid; t < 3*SQ; t += 512){
    int c = t / SQ; int r2 = t - c*SQ; int rr = r2 / EXT; int cc = r2 - rr*EXT;
    sXp[t] = Xp[c*82944 + (bi+rr)*288 + (bj+cc)];
  }
  __syncthreads();

  #pragma unroll
  for (int c = 0; c < 3; ++c){
    float acc[5][5];
    #pragma unroll
    for (int u = 0; u < 5; ++u)
      #pragma unroll
      for (int v = 0; v < 5; ++v) acc[u][v] = 0.f;
    #pragma unroll
    for (int m = 0; m < 2; ++m){
      if (m < nk){
        const float* pb = &sXp[c*SQ + (ly + ndy[m])*EXT + lx + ndx[m]];
        float g = wgt[m];
        #pragma unroll
        for (int u = 0; u < 5; ++u)
          #pragma unroll
          for (int v = 0; v < 5; ++v)
            acc[u][v] = fmaf(g, pb[u*EXT + v], acc[u][v]);
      }
    }
    #pragma unroll
    for (int u = 0; u < 5; ++u)
      #pragma unroll
      for (int v = 0; v < 5; ++v)
        atomicAdd(&sFold[((ly+u)*12 + (lx+v))*3 + c], acc[u][v]);
  }
  __syncthreads();
  for (int t = tid; t < 432; t += 512){
    int c = t % 3; int rc = t / 3; int rr = rc / 12; int cc = rc - rr*12;
    atomicAdd(&accG[c*67600 + (bi+rr)*260 + (bj+cc)], sFold[t]);
  }
}

__global__ void k_finish(const float* __restrict__ accG, float* __restrict__ out){
  int idx = blockIdx.x * 256 + threadIdx.x;
  if (idx >= 3*65536) return;
  int c = idx >> 16; int rem = idx & 65535; int y = rem >> 8; int x = rem & 255;
  int cy = min(4, y + 2) - max(0, y - 253) + 1;
  int cx = min(4, x + 2) - max(0, x - 253) + 1;
  float v = accG[c*67600 + (y+2)*260 + (x+2)] / (float)(cy * cx);
  out[idx] = 127.5f * v + 127.5f;
}

extern "C" void kernel_launch(void* const* d_in, const int* in_sizes, int n_in,
                              void* d_out, int out_size, void* d_ws, size_t ws_size,
                              hipStream_t stream) {
  const float* noisy = (const float*)d_in[0];
  const float* sigma = (const float*)d_in[1];
  const float* wgray = (const float*)d_in[2];
  float* out  = (float*)d_out;
  float* Xp   = (float*)d_ws;                  // 3*288*288 floats
  float* accG = Xp + 3*288*288;                // 3*260*260 floats

  k_prep<<<dim3(793), dim3(256), 0, stream>>>(noisy, Xp, accG);
  k_search<<<dim3(32, 32), dim3(512), 0, stream>>>(Xp, sigma, wgray, accG);
  k_finish<<<dim3(768), dim3(256), 0, stream>>>(accG, out);
}

// Round 6
// 247.733 us; speedup vs baseline: 3.3464x; 1.3509x over previous
//
#include <hip/hip_runtime.h>

#define EXT 40
#define SQ (EXT*EXT)

typedef float v2f __attribute__((ext_vector_type(2)));

__device__ __forceinline__ unsigned um_min(unsigned a, unsigned b){ return a < b ? a : b; }
__device__ __forceinline__ unsigned um_max(unsigned a, unsigned b){ return a > b ? a : b; }
__device__ __forceinline__ unsigned med3u(unsigned a, unsigned b, unsigned c){
  unsigned d;
  asm("v_med3_u32 %0, %1, %2, %3" : "=v"(d) : "v"(a), "v"(b), "v"(c));
  return d;
}

// arr sorted descending (arr[0] = largest of the kept 14 smallest).
// Insert key, drop the max of the 15. med3 network: 15 ops, dep depth 2.
__device__ __forceinline__ void insert14(unsigned (&a)[14], unsigned key){
  unsigned kp  = um_min(key, a[0]);
  unsigned n0  = um_max(a[1], kp);
  unsigned n13 = um_min(a[13], kp);
  unsigned nn[12];
  #pragma unroll
  for (int i = 1; i <= 12; ++i) nn[i-1] = med3u(a[i], a[i+1], kp);
  a[0] = n0;
  #pragma unroll
  for (int i = 1; i <= 12; ++i) a[i] = nn[i-1];
  a[13] = n13;
}

// Reflect-padded rescaled image Xp[3][288][288] (means cancel -> skipped),
// plus zero-init of the global fold accumulator.
__global__ void k_prep(const float* __restrict__ noisy, float* __restrict__ Xp,
                       float* __restrict__ accG){
  int idx = blockIdx.x * 256 + threadIdx.x;
  if (idx < 3*260*260) accG[idx] = 0.f;
  if (idx >= 288*288) return;
  int P = idx / 288, Q = idx - P*288;
  int sy = P - 16; sy = sy < 0 ? -sy : sy; sy = sy > 255 ? 510 - sy : sy;
  int sx = Q - 16; sx = sx < 0 ? -sx : sx; sx = sx > 255 ? 510 - sx : sx;
  const float inv = 1.0f / 127.5f;
  int src = sy*256 + sx;
  #pragma unroll
  for (int c = 0; c < 3; ++c)
    Xp[c*82944 + idx] = noisy[c*65536 + src] * inv - 1.0f;
}

// One dx step, ring phase R = dx%5. Row-paired packed math:
// rows (0,1) and (2,3) live in v2f (v_pk_fma_f32), row 4 scalar.
// New column loads: 2x ds_read2_b32 + 1x ds_read_b32 (offsets 0/40/80/120/160 dw).
template<int R>
__device__ __forceinline__ void ssd_step(const float* colbase, unsigned key_o,
                                         const v2f (&cpA)[5], const v2f (&cpB)[5],
                                         const float (&cp4)[5], float cpsq,
                                         v2f (&wA)[5], v2f (&wB)[5], float (&w4)[5],
                                         float (&ring)[5], float& winsq,
                                         unsigned (&arr)[14]){
  constexpr int nc = (R + 4) % 5;
  v2f n01; n01.x = colbase[0];     n01.y = colbase[EXT];
  v2f n23; n23.x = colbase[2*EXT]; n23.y = colbase[3*EXT];
  float n4 = colbase[4*EXT];
  wA[nc] = n01; wB[nc] = n23; w4[nc] = n4;
  v2f q = __builtin_elementwise_fma(n23, n23, n01*n01);
  float nssq = fmaf(n4, n4, q.x + q.y);
  winsq += (nssq - ring[nc]);
  ring[nc] = nssq;
  v2f accA = cpA[0]*wA[R];
  v2f accB = cpB[0]*wB[R];
  float sacc = cp4[0]*w4[R];
  #pragma unroll
  for (int v = 1; v < 5; ++v){
    accA = __builtin_elementwise_fma(cpA[v], wA[(R+v)%5], accA);
    accB = __builtin_elementwise_fma(cpB[v], wB[(R+v)%5], accB);
    sacc = fmaf(cp4[v], w4[(R+v)%5], sacc);
  }
  float cross = (accA.x + accA.y) + ((accB.x + accB.y) + sacc);
  float dist = fmaf(cross, -2.0f, cpsq + winsq);
  dist = fmaxf(dist, 0.0f);   // cancellation guard
  insert14(arr, (__float_as_uint(dist) & 0xFFFFFC00u) | key_o);
}

// One 8x8 pixel tile per 256-thread block; 4 waves split the 29 dy rows.
// R2-proven shell (187us): launch_bounds(256,4), 38.4KB LDS, 4 blocks/CU.
__global__ __launch_bounds__(256, 4) void k_search(const float* __restrict__ Xp,
      const float* __restrict__ sigma, const float* __restrict__ wgray,
      float* __restrict__ accG){
  __shared__ float sXp[3*SQ];        // 19200 B color tile
  __shared__ float sG[SQ];           //  6400 B grayscale tile
  __shared__ unsigned sCand[3*64*14];// 10752 B per-wave candidates
  __shared__ float sWsum[64];
  __shared__ float sFold[12*12*3];

  const int tid = threadIdx.x;
  const int w = tid >> 6, l = tid & 63;
  const int ly = l >> 3, lx = l & 7;
  const int bi = blockIdx.y * 8, bj = blockIdx.x * 8;

  for (int t = tid; t < 3*SQ; t += 256){
    int c = t / SQ; int r2 = t - c*SQ; int rr = r2 / EXT; int cc = r2 - rr*EXT;
    sXp[t] = Xp[c*82944 + (bi+rr)*288 + (bj+cc)];
  }
  if (tid < 64) sWsum[tid] = 0.f;
  for (int t = tid; t < 432; t += 256) sFold[t] = 0.f;
  __syncthreads();
  const float w0 = wgray[0], w1 = wgray[1], w2 = wgray[2];
  for (int t = tid; t < SQ; t += 256)
    sG[t] = w0*sXp[t] + w1*sXp[SQ+t] + w2*sXp[2*SQ+t];
  __syncthreads();

  // center 5x5 patch, row-paired, + squared norm
  v2f cpA[5], cpB[5]; float cp4[5];
  const float* cpb = &sG[(14 + ly)*EXT + 14 + lx];
  #pragma unroll
  for (int v = 0; v < 5; ++v){
    v2f a; a.x = cpb[v];       a.y = cpb[EXT+v];   cpA[v] = a;
    v2f b; b.x = cpb[2*EXT+v]; b.y = cpb[3*EXT+v]; cpB[v] = b;
    cp4[v] = cpb[4*EXT+v];
  }
  v2f s2 = cpA[0]*cpA[0];
  float s1 = cp4[0]*cp4[0];
  #pragma unroll
  for (int v = 0; v < 5; ++v){
    if (v) { s2 = __builtin_elementwise_fma(cpA[v], cpA[v], s2);
             s1 = fmaf(cp4[v], cp4[v], s1); }
    s2 = __builtin_elementwise_fma(cpB[v], cpB[v], s2);
  }
  const float cpsq = s2.x + s2.y + s1;

  unsigned arr[14];
  #pragma unroll
  for (int k = 0; k < 14; ++k) arr[k] = 0xFFFFFFFFu;

  // rows per wave: {8,7,7,7}
  const int dy0 = (w == 0) ? 0 : 1 + 7*w;
  const int dy1 = dy0 + ((w == 0) ? 8 : 7);

  #pragma unroll 1
  for (int dy = dy0; dy < dy1; ++dy){
    const float* rowbase = &sG[(dy + ly)*EXT + lx];
    v2f wA[5], wB[5]; float w4[5], ring[5], winsq;
    #pragma unroll
    for (int v = 0; v < 4; ++v){
      const float* cb = rowbase + v;
      v2f a; a.x = cb[0];     a.y = cb[EXT];   wA[v] = a;
      v2f b; b.x = cb[2*EXT]; b.y = cb[3*EXT]; wB[v] = b;
      w4[v] = cb[4*EXT];
      v2f q = __builtin_elementwise_fma(b, b, a*a);
      ring[v] = fmaf(w4[v], w4[v], q.x + q.y);
    }
    ring[4] = 0.f;
    winsq = (ring[0] + ring[1]) + (ring[2] + ring[3]);
    const unsigned obase = (unsigned)(dy * 29);

    #pragma unroll 1
    for (int b5 = 0; b5 < 5; ++b5){          // 5 blocks of 5 (ring period)
      int dxb = b5 * 5;
      const float* c0 = rowbase + dxb + 4;
      unsigned ob = obase + (unsigned)dxb;
      ssd_step<0>(c0+0, ob+0, cpA,cpB,cp4,cpsq, wA,wB,w4, ring,winsq, arr);
      ssd_step<1>(c0+1, ob+1, cpA,cpB,cp4,cpsq, wA,wB,w4, ring,winsq, arr);
      ssd_step<2>(c0+2, ob+2, cpA,cpB,cp4,cpsq, wA,wB,w4, ring,winsq, arr);
      ssd_step<3>(c0+3, ob+3, cpA,cpB,cp4,cpsq, wA,wB,w4, ring,winsq, arr);
      ssd_step<4>(c0+4, ob+4, cpA,cpB,cp4,cpsq, wA,wB,w4, ring,winsq, arr);
    }
    const float* c0 = rowbase + 25 + 4;       // tail: dx = 25..28
    ssd_step<0>(c0+0, obase+25, cpA,cpB,cp4,cpsq, wA,wB,w4, ring,winsq, arr);
    ssd_step<1>(c0+1, obase+26, cpA,cpB,cp4,cpsq, wA,wB,w4, ring,winsq, arr);
    ssd_step<2>(c0+2, obase+27, cpA,cpB,cp4,cpsq, wA,wB,w4, ring,winsq, arr);
    ssd_step<3>(c0+3, obase+28, cpA,cpB,cp4,cpsq, wA,wB,w4, ring,winsq, arr);
  }

  // merge 4 waves' top-14 -> global top-14
  if (w){
    #pragma unroll
    for (int k = 0; k < 14; ++k) sCand[((w-1)*64 + l)*14 + k] = arr[k];
  }
  __syncthreads();
  if (!w){
    for (int q = 0; q < 3; ++q)
      #pragma unroll
      for (int k = 0; k < 14; ++k)
        insert14(arr, sCand[(q*64 + l)*14 + k]);
    #pragma unroll
    for (int k = 0; k < 14; ++k) sCand[l*14 + k] = arr[k];
  }
  __syncthreads();

  // ---- phase 2: softmax weights + weighted patch aggregation ----
  float sg = sigma[0] * (1.0f / 127.5f);
  const float invT = 1.0f / (sg*sg*25.0f + 1e-8f);
  const float dmin = __uint_as_float(sCand[l*14 + 13] & 0xFFFFFC00u);

  float wgt[4]; int ndy[4], ndx[4];
  const int nk = (w < 2) ? 4 : 3;          // ranks {w, w+4, w+8, (w+12)}
  float Sp = 0.f;
  #pragma unroll
  for (int m = 0; m < 4; ++m){
    if (m < nk){
      unsigned kk = sCand[l*14 + (w + 4*m)];
      float d = __uint_as_float(kk & 0xFFFFFC00u);
      int o = (int)(kk & 0x3FFu);
      wgt[m] = expf(-(d - dmin) * invT);
      ndy[m] = o / 29; ndx[m] = o - ndy[m]*29;
      Sp += wgt[m];
    }
  }
  atomicAdd(&sWsum[l], Sp);
  __syncthreads();
  const float invS = 1.0f / sWsum[l];
  #pragma unroll
  for (int m = 0; m < 4; ++m) if (m < nk) wgt[m] *= invS;

  #pragma unroll
  for (int c = 0; c < 3; ++c){
    float acc[5][5];
    #pragma unroll
    for (int u = 0; u < 5; ++u)
      #pragma unroll
      for (int v = 0; v < 5; ++v) acc[u][v] = 0.f;
    #pragma unroll
    for (int m = 0; m < 4; ++m){
      if (m < nk){
        const float* pb = &sXp[c*SQ + (ly + ndy[m])*EXT + lx + ndx[m]];
        float g = wgt[m];
        #pragma unroll
        for (int u = 0; u < 5; ++u)
          #pragma unroll
          for (int v = 0; v < 5; ++v)
            acc[u][v] = fmaf(g, pb[u*EXT + v], acc[u][v]);
      }
    }
    #pragma unroll
    for (int u = 0; u < 5; ++u)
      #pragma unroll
      for (int v = 0; v < 5; ++v)
        atomicAdd(&sFold[((ly+u)*12 + (lx+v))*3 + c], acc[u][v]);
  }
  __syncthreads();
  for (int t = tid; t < 432; t += 256){
    int c = t % 3; int rc = t / 3; int rr = rc / 12; int cc = rc - rr*12;
    atomicAdd(&accG[c*67600 + (bi+rr)*260 + (bj+cc)], sFold[t]);
  }
}

__global__ void k_finish(const float* __restrict__ accG, float* __restrict__ out){
  int idx = blockIdx.x * 256 + threadIdx.x;
  if (idx >= 3*65536) return;
  int c = idx >> 16; int rem = idx & 65535; int y = rem >> 8; int x = rem & 255;
  int cy = min(4, y + 2) - max(0, y - 253) + 1;
  int cx = min(4, x + 2) - max(0, x - 253) + 1;
  float v = accG[c*67600 + (y+2)*260 + (x+2)] / (float)(cy * cx);
  out[idx] = 127.5f * v + 127.5f;
}

extern "C" void kernel_launch(void* const* d_in, const int* in_sizes, int n_in,
                              void* d_out, int out_size, void* d_ws, size_t ws_size,
                              hipStream_t stream) {
  const float* noisy = (const float*)d_in[0];
  const float* sigma = (const float*)d_in[1];
  const float* wgray = (const float*)d_in[2];
  float* out  = (float*)d_out;
  float* Xp   = (float*)d_ws;                  // 3*288*288 floats
  float* accG = Xp + 3*288*288;                // 3*260*260 floats

  k_prep<<<dim3(793), dim3(256), 0, stream>>>(noisy, Xp, accG);
  k_search<<<dim3(32, 32), dim3(256), 0, stream>>>(Xp, sigma, wgray, accG);
  k_finish<<<dim3(768), dim3(256), 0, stream>>>(accG, out);
}

// Round 7
// 234.689 us; speedup vs baseline: 3.5324x; 1.0556x over previous
//
#include <hip/hip_runtime.h>

#define EXT 40
#define SQ (EXT*EXT)

__device__ __forceinline__ unsigned um_min(unsigned a, unsigned b){ return a < b ? a : b; }
__device__ __forceinline__ unsigned um_max(unsigned a, unsigned b){ return a > b ? a : b; }
__device__ __forceinline__ unsigned med3u(unsigned a, unsigned b, unsigned c){
  unsigned d;
  asm("v_med3_u32 %0, %1, %2, %3" : "=v"(d) : "v"(a), "v"(b), "v"(c));
  return d;
}

// arr sorted descending (arr[0] = largest of the kept 14 smallest).
// Insert key, drop the max of the 15. med3 network: 15 ops, dep depth 2.
__device__ __forceinline__ void insert14(unsigned (&a)[14], unsigned key){
  unsigned kp  = um_min(key, a[0]);
  unsigned n0  = um_max(a[1], kp);
  unsigned n13 = um_min(a[13], kp);
  unsigned nn[12];
  #pragma unroll
  for (int i = 1; i <= 12; ++i) nn[i-1] = med3u(a[i], a[i+1], kp);
  a[0] = n0;
  #pragma unroll
  for (int i = 1; i <= 12; ++i) a[i] = nn[i-1];
  a[13] = n13;
}

// Reflect-padded rescaled image Xp[3][288][288] (means cancel -> skipped),
// plus zero-init of the global fold accumulator.
__global__ void k_prep(const float* __restrict__ noisy, float* __restrict__ Xp,
                       float* __restrict__ accG){
  int idx = blockIdx.x * 256 + threadIdx.x;
  if (idx < 3*260*260) accG[idx] = 0.f;
  if (idx >= 288*288) return;
  int P = idx / 288, Q = idx - P*288;
  int sy = P - 16; sy = sy < 0 ? -sy : sy; sy = sy > 255 ? 510 - sy : sy;
  int sx = Q - 16; sx = sx < 0 ? -sx : sx; sx = sx > 255 ? 510 - sx : sx;
  const float inv = 1.0f / 127.5f;
  int src = sy*256 + sx;
  #pragma unroll
  for (int c = 0; c < 3; ++c)
    Xp[c*82944 + idx] = noisy[c*65536 + src] * inv - 1.0f;
}

// ---- software-pipelined SSD row: 8-slot column ring, loads 2 steps ahead ----
template<int COL>
__device__ __forceinline__ void load_col(const float* rowbase, float (&win)[5][8]){
  #pragma unroll
  for (int u = 0; u < 5; ++u) win[u][COL & 7] = rowbase[u*EXT + COL];
}

template<int DX>
__device__ __forceinline__ void math_step(unsigned obase, const float (&cp)[5][5],
    float cpsq, const float (&win)[5][8], float (&ssq)[8], unsigned (&arr)[14]){
  constexpr int s4 = (DX + 4) & 7;
  float ns = win[0][s4]*win[0][s4];
  #pragma unroll
  for (int u = 1; u < 5; ++u) ns = fmaf(win[u][s4], win[u][s4], ns);
  ssq[s4] = ns;
  // winsq recomputed from ring: no loop-carried serial chain
  float winsq = ((ssq[DX&7] + ssq[(DX+1)&7]) + (ssq[(DX+2)&7] + ssq[(DX+3)&7])) + ns;
  float c0 = cp[0][0]*win[0][DX&7];
  float c1 = cp[1][0]*win[1][DX&7];
  float c2 = cp[2][0]*win[2][DX&7];
  float c3 = cp[3][0]*win[3][DX&7];
  float c4 = cp[4][0]*win[4][DX&7];
  #pragma unroll
  for (int v = 1; v < 5; ++v){
    c0 = fmaf(cp[0][v], win[0][(DX+v)&7], c0);
    c1 = fmaf(cp[1][v], win[1][(DX+v)&7], c1);
    c2 = fmaf(cp[2][v], win[2][(DX+v)&7], c2);
    c3 = fmaf(cp[3][v], win[3][(DX+v)&7], c3);
    c4 = fmaf(cp[4][v], win[4][(DX+v)&7], c4);
  }
  float cross = ((c0 + c1) + (c2 + c3)) + c4;
  float dist = fmaf(cross, -2.0f, cpsq + winsq);
  dist = fmaxf(dist, 0.0f);   // cancellation guard
  insert14(arr, (__float_as_uint(dist) & 0xFFFFFC00u) | (obase + (unsigned)DX));
}

template<int DX>
__device__ __forceinline__ void pipe_steps(const float* rowbase, unsigned obase,
    const float (&cp)[5][5], float cpsq, float (&win)[5][8], float (&ssq)[8],
    unsigned (&arr)[14]){
  if constexpr (DX < 29){
    if constexpr (DX + 6 <= 32) load_col<DX+6>(rowbase, win);  // 2 steps ahead
    math_step<DX>(obase, cp, cpsq, win, ssq, arr);
    pipe_steps<DX+1>(rowbase, obase, cp, cpsq, win, ssq, arr);
  }
}

// One 8x8 pixel tile per 256-thread block; 4 waves split the 29 dy rows.
// launch_bounds(256,2): VGPR cap 256 -> allocator free (~110 live), no
// mov-juggling, deep load hoisting. LDS 38.4KB caps residency at 4 blocks/CU
// (= 4 waves/EU) independent of VGPR as long as <=128.
__global__ __launch_bounds__(256, 2) void k_search(const float* __restrict__ Xp,
      const float* __restrict__ sigma, const float* __restrict__ wgray,
      float* __restrict__ accG){
  __shared__ float sXp[3*SQ];        // 19200 B color tile
  __shared__ float sG[SQ];           //  6400 B grayscale tile
  __shared__ unsigned sCand[3*64*14];// 10752 B per-wave candidates
  __shared__ float sWsum[64];
  __shared__ float sFold[12*12*3];

  const int tid = threadIdx.x;
  const int w = tid >> 6, l = tid & 63;
  const int ly = l >> 3, lx = l & 7;
  const int bi = blockIdx.y * 8, bj = blockIdx.x * 8;

  for (int t = tid; t < 3*SQ; t += 256){
    int c = t / SQ; int r2 = t - c*SQ; int rr = r2 / EXT; int cc = r2 - rr*EXT;
    sXp[t] = Xp[c*82944 + (bi+rr)*288 + (bj+cc)];
  }
  if (tid < 64) sWsum[tid] = 0.f;
  for (int t = tid; t < 432; t += 256) sFold[t] = 0.f;
  __syncthreads();
  const float w0 = wgray[0], w1 = wgray[1], w2 = wgray[2];
  for (int t = tid; t < SQ; t += 256)
    sG[t] = w0*sXp[t] + w1*sXp[SQ+t] + w2*sXp[2*SQ+t];
  __syncthreads();

  // center 5x5 grayscale patch + squared norm
  float cp[5][5];
  #pragma unroll
  for (int u = 0; u < 5; ++u)
    #pragma unroll
    for (int v = 0; v < 5; ++v)
      cp[u][v] = sG[(14 + ly + u)*EXT + 14 + lx + v];
  float cpsq = 0.f;
  #pragma unroll
  for (int v = 0; v < 5; ++v){
    float cs = cp[0][v]*cp[0][v];
    #pragma unroll
    for (int u = 1; u < 5; ++u) cs = fmaf(cp[u][v], cp[u][v], cs);
    cpsq += cs;
  }

  unsigned arr[14];
  #pragma unroll
  for (int k = 0; k < 14; ++k) arr[k] = 0xFFFFFFFFu;

  // rows per wave: {7,8,7,7} -- merge-wave 0 is not the straggler
  const int dy0 = (w == 0) ? 0 : (w == 1 ? 7 : (w == 2 ? 15 : 22));
  const int nrows = (w == 1) ? 8 : 7;

  #pragma unroll 1
  for (int r = 0; r < nrows; ++r){
    const int dy = dy0 + r;
    const float* rowbase = &sG[(dy + ly)*EXT + lx];
    float win[5][8], ssq[8];
    load_col<0>(rowbase, win); load_col<1>(rowbase, win);
    load_col<2>(rowbase, win); load_col<3>(rowbase, win);
    load_col<4>(rowbase, win); load_col<5>(rowbase, win);
    #pragma unroll
    for (int v = 0; v < 4; ++v){
      float cs = win[0][v]*win[0][v];
      #pragma unroll
      for (int u = 1; u < 5; ++u) cs = fmaf(win[u][v], win[u][v], cs);
      ssq[v] = cs;
    }
    pipe_steps<0>(rowbase, (unsigned)(dy*29), cp, cpsq, win, ssq, arr);
  }

  // merge 4 waves' top-14 -> global top-14
  if (w){
    #pragma unroll
    for (int k = 0; k < 14; ++k) sCand[((w-1)*64 + l)*14 + k] = arr[k];
  }
  __syncthreads();
  if (!w){
    for (int q = 0; q < 3; ++q)
      #pragma unroll
      for (int k = 0; k < 14; ++k)
        insert14(arr, sCand[(q*64 + l)*14 + k]);
    #pragma unroll
    for (int k = 0; k < 14; ++k) sCand[l*14 + k] = arr[k];
  }
  __syncthreads();

  // ---- phase 2: softmax weights + weighted patch aggregation ----
  float sg = sigma[0] * (1.0f / 127.5f);
  const float invT = 1.0f / (sg*sg*25.0f + 1e-8f);
  const float dmin = __uint_as_float(sCand[l*14 + 13] & 0xFFFFFC00u);

  float wgt[4]; int ndy[4], ndx[4];
  const int nk = (w < 2) ? 4 : 3;          // ranks {w, w+4, w+8, (w+12)}
  float Sp = 0.f;
  #pragma unroll
  for (int m = 0; m < 4; ++m){
    if (m < nk){
      unsigned kk = sCand[l*14 + (w + 4*m)];
      float d = __uint_as_float(kk & 0xFFFFFC00u);
      int o = (int)(kk & 0x3FFu);
      wgt[m] = expf(-(d - dmin) * invT);
      ndy[m] = o / 29; ndx[m] = o - ndy[m]*29;
      Sp += wgt[m];
    }
  }
  atomicAdd(&sWsum[l], Sp);
  __syncthreads();
  const float invS = 1.0f / sWsum[l];
  #pragma unroll
  for (int m = 0; m < 4; ++m) if (m < nk) wgt[m] *= invS;

  #pragma unroll
  for (int c = 0; c < 3; ++c){
    float acc[5][5];
    #pragma unroll
    for (int u = 0; u < 5; ++u)
      #pragma unroll
      for (int v = 0; v < 5; ++v) acc[u][v] = 0.f;
    #pragma unroll
    for (int m = 0; m < 4; ++m){
      if (m < nk){
        const float* pb = &sXp[c*SQ + (ly + ndy[m])*EXT + lx + ndx[m]];
        float g = wgt[m];
        #pragma unroll
        for (int u = 0; u < 5; ++u)
          #pragma unroll
          for (int v = 0; v < 5; ++v)
            acc[u][v] = fmaf(g, pb[u*EXT + v], acc[u][v]);
      }
    }
    #pragma unroll
    for (int u = 0; u < 5; ++u)
      #pragma unroll
      for (int v = 0; v < 5; ++v)
        atomicAdd(&sFold[((ly+u)*12 + (lx+v))*3 + c], acc[u][v]);
  }
  __syncthreads();
  for (int t = tid; t < 432; t += 256){
    int c = t % 3; int rc = t / 3; int rr = rc / 12; int cc = rc - rr*12;
    atomicAdd(&accG[c*67600 + (bi+rr)*260 + (bj+cc)], sFold[t]);
  }
}

__global__ void k_finish(const float* __restrict__ accG, float* __restrict__ out){
  int idx = blockIdx.x * 256 + threadIdx.x;
  if (idx >= 3*65536) return;
  int c = idx >> 16; int rem = idx & 65535; int y = rem >> 8; int x = rem & 255;
  int cy = min(4, y + 2) - max(0, y - 253) + 1;
  int cx = min(4, x + 2) - max(0, x - 253) + 1;
  float v = accG[c*67600 + (y+2)*260 + (x+2)] / (float)(cy * cx);
  out[idx] = 127.5f * v + 127.5f;
}

extern "C" void kernel_launch(void* const* d_in, const int* in_sizes, int n_in,
                              void* d_out, int out_size, void* d_ws, size_t ws_size,
                              hipStream_t stream) {
  const float* noisy = (const float*)d_in[0];
  const float* sigma = (const float*)d_in[1];
  const float* wgray = (const float*)d_in[2];
  float* out  = (float*)d_out;
  float* Xp   = (float*)d_ws;                  // 3*288*288 floats
  float* accG = Xp + 3*288*288;                // 3*260*260 floats

  k_prep<<<dim3(793), dim3(256), 0, stream>>>(noisy, Xp, accG);
  k_search<<<dim3(32, 32), dim3(256), 0, stream>>>(Xp, sigma, wgray, accG);
  k_finish<<<dim3(768), dim3(256), 0, stream>>>(accG, out);
}